// Round 9
// baseline (502.545 us; speedup 1.0000x reference)
//
#include <hip/hip_runtime.h>

// Bit-exact recipe (locked by R1-R7 bisection, absmax 0.0078 vs 0.106 thr):
//   cube  = (x*x)*x ;  j-sum = T3  ((m0+m4)+m2)+(m1+m3) ;  no fma anywhere
//   coef  = sequential ascending fp32 prod (b==j -> 1.0), IEEE divide
//   i-sum = sequential ascending, unfused mul/add
// R8 accounting: dur 85 = 41 (harness d_ws 256MB poison fill, immovable)
//   + ~35 eval + 3 prep + overhead. Eval was s_load-latency bound (7 scalar
//   dwords/iter vs 28 cyc VALU/iter -> lgkmcnt stalls).
// R9: single fused kernel; 4 batch-elems/thread (112 cyc VALU/iter) hides
//   broadcast LDS latency; coef built in-block (no prep launch, no global
//   coef round-trip); wave-uniform LDS reads = conflict-free broadcast.
#pragma clang fp contract(off)

#define FEATURES   512
#define N_BSPLINES 64
#define N_KNOTS    68   // N_BSPLINES + DEGREE + 1
#define WINDOW     5    // DEGREE + 2
#define BATCH      2048

#define QPT 4          // batch elements per thread
#define NT  256        // threads per block

__device__ __forceinline__ float cube_f32(float r) {
    float s = r * r;
    return s * r;
}

__global__ __launch_bounds__(NT, 4) void bspline_fused(
    const float* __restrict__ x, const float* __restrict__ knots,
    const float* __restrict__ weights, float* __restrict__ out)
{
    __shared__ float kS[N_KNOTS];
    __shared__ float wS[N_BSPLINES];
    __shared__ float cS[N_BSPLINES][8];   // coef row padded 5->8 (16B-aligned b128)

    const int tid  = threadIdx.x;
    const int f    = blockIdx.x & (FEATURES - 1);   // uniform per block
    const int half = blockIdx.x >> 9;               // 0..1
    const int bb   = half * (BATCH / 2) + tid;      // thread's first batch row

    // Issue x loads immediately; latency overlaps the coef phase.
    float xq[QPT];
    #pragma unroll
    for (int p = 0; p < QPT; ++p)
        xq[p] = x[(bb + p * NT) * FEATURES + f];

    if (tid < N_KNOTS)    kS[tid] = knots[f * N_KNOTS + tid];
    if (tid < N_BSPLINES) wS[tid] = weights[f * N_BSPLINES + tid];
    __syncthreads();

    // In-block coef table: 320 entries over 256 threads (bit-identical to ref:
    // sequential ascending fp32 product, b==j factor is the exact 1.0, IEEE div).
    for (int e = tid; e < N_BSPLINES * WINDOW; e += NT) {
        int i = e / WINDOW, j = e % WINDOW;
        float kj = kS[i + j];
        float prod = 1.0f;
        #pragma unroll
        for (int b = 0; b < WINDOW; ++b) {
            float df = (b == j) ? 1.0f : (kS[i + b] - kj);
            prod = prod * df;
        }
        cS[i][j] = 1.0f / prod;
    }
    __syncthreads();

    float acc[QPT];
    float r0[QPT], r1[QPT], r2[QPT], r3[QPT], r4[QPT];
    #pragma unroll
    for (int p = 0; p < QPT; ++p) {
        acc[p] = 0.0f;
        r0[p] = cube_f32(fmaxf(xq[p] - kS[0], 0.0f));
        r1[p] = cube_f32(fmaxf(xq[p] - kS[1], 0.0f));
        r2[p] = cube_f32(fmaxf(xq[p] - kS[2], 0.0f));
        r3[p] = cube_f32(fmaxf(xq[p] - kS[3], 0.0f));
        r4[p] = cube_f32(fmaxf(xq[p] - kS[4], 0.0f));
    }

    #pragma unroll 16
    for (int i = 0; i < N_BSPLINES; ++i) {
        // wave-uniform addresses -> conflict-free LDS broadcast
        const float c0 = cS[i][0];
        const float c1 = cS[i][1];
        const float c2 = cS[i][2];
        const float c3 = cS[i][3];
        const float c4 = cS[i][4];
        const float wi = wS[i];
        const float kn = (i < N_BSPLINES - 1) ? kS[i + 5] : 0.0f;
        #pragma unroll
        for (int p = 0; p < QPT; ++p) {
            float m0 = r0[p] * c0;
            float m1 = r1[p] * c1;
            float m2 = r2[p] * c2;
            float m3 = r3[p] * c3;
            float m4 = r4[p] * c4;
            // T3: masked-tail fold of m4 into lane 0, then shuffle-halves
            float t04  = m0 + m4;
            float t042 = t04 + m2;
            float t13  = m1 + m3;
            float sp   = t042 + t13;
            acc[p] = acc[p] + sp * wi;    // unfused, sequential i-sum
            r0[p] = r1[p]; r1[p] = r2[p]; r2[p] = r3[p]; r3[p] = r4[p];
            if (i < N_BSPLINES - 1)
                r4[p] = cube_f32(fmaxf(xq[p] - kn, 0.0f));
        }
    }

    #pragma unroll
    for (int p = 0; p < QPT; ++p)
        out[(bb + p * NT) * FEATURES + f] = acc[p];
}

extern "C" void kernel_launch(void* const* d_in, const int* in_sizes, int n_in,
                              void* d_out, int out_size, void* d_ws, size_t ws_size,
                              hipStream_t stream) {
    const float* x       = (const float*)d_in[0];   // (2048, 512)
    const float* knots   = (const float*)d_in[1];   // (512, 68)
    const float* weights = (const float*)d_in[2];   // (512, 64)
    float*       out     = (float*)d_out;           // (2048, 512)

    const int blocks = FEATURES * 2;                // 1024: (f, batch-half)
    bspline_fused<<<blocks, NT, 0, stream>>>(x, knots, weights, out);
}

// Round 10
// 110.327 us; speedup vs baseline: 4.5551x; 4.5551x over previous
//
#include <hip/hip_runtime.h>

// Bit-exact recipe (locked R1-R7, absmax 0.0078 vs 0.106 thr):
//   cube  = (x*x)*x ;  j-sum = T3  ((m0+m4)+m2)+(m1+m3) ;  no fma anywhere
//   coef  = sequential ascending fp32 prod (b==j -> 1.0), IEEE divide
//   i-sum = sequential ascending, unfused mul/add
// R9 lesson (465us, 554MB FETCH): lanes MUST map to f for global coalescing.
// R10 = R7 structure + (1) conflict-free build-phase lane mapping (ft=e&15),
//   (2) packed per-ft table rows [i][c0..c4,w,kn,pad] read as 2x ds_read_b128,
//   (3) QPT=2 / TILE_B=32 -> 2048 blocks, 4 blocks/CU by LDS.
#pragma clang fp contract(off)

#define FEATURES   512
#define N_BSPLINES 64
#define N_KNOTS    68   // N_BSPLINES + DEGREE + 1
#define WINDOW     5    // DEGREE + 2
#define BATCH      2048

#define TF 16          // features per block (lane low bits -> 64B line per 16 lanes)
#define TB 32          // batch rows per block
#define QPT 2          // rows per thread
#define NT 256
#define TSTRIDE 516    // floats per ft table row: 64*8 + 4 pad (16B aligned, 2-way banks)

__device__ __forceinline__ float cube_f32(float r) {
    float s = r * r;
    return s * r;
}

__global__ __launch_bounds__(NT) void bspline_fused(
    const float* __restrict__ x, const float* __restrict__ knots,
    const float* __restrict__ weights, float* __restrict__ out)
{
    __shared__ float kL[N_KNOTS * TF];     // [t][ft]
    __shared__ float tab[TF * TSTRIDE];    // [ft][i*8 + c]  c: 0-4 coef, 5 w, 6 kn

    const int tid  = threadIdx.x;
    const int fblk = blockIdx.x & (FEATURES / TF - 1);   // 0..31
    const int bblk = blockIdx.x >> 5;                    // 0..63
    const int f0   = fblk * TF;
    const int b0   = bblk * TB;

    const int ft = tid & (TF - 1);
    const int bt = tid >> 4;               // 0..15

    // x loads issued early; latency overlaps staging + coef build.
    float xq[QPT];
    #pragma unroll
    for (int q = 0; q < QPT; ++q)
        xq[q] = x[(b0 + bt + q * 16) * FEATURES + f0 + ft];

    // Stage knots [t][ft]; ft=e&15 -> consecutive lanes hit consecutive LDS words.
    for (int e = tid; e < N_KNOTS * TF; e += NT) {
        int ff = e & (TF - 1), t = e >> 4;
        kL[t * TF + ff] = knots[(f0 + ff) * N_KNOTS + t];
    }
    __syncthreads();

    // Coef build (bit-exact: sequential ascending fp32 product, b==j -> exact
    // 1.0, IEEE fp32 divide). Conflict-free: lane-adjacent e -> same m, ff+1.
    for (int e = tid; e < N_BSPLINES * WINDOW * TF; e += NT) {
        int ff = e & (TF - 1);
        int m  = e >> 4;                   // 0..319
        int i = m / WINDOW, j = m % WINDOW;
        float kj = kL[(i + j) * TF + ff];
        float prod = 1.0f;
        #pragma unroll
        for (int b = 0; b < WINDOW; ++b) {
            float df = (b == j) ? 1.0f : (kL[(i + b) * TF + ff] - kj);
            prod = prod * df;
        }
        tab[ff * TSTRIDE + i * 8 + j] = 1.0f / prod;
    }
    // w and next-knot slots.
    for (int e = tid; e < N_BSPLINES * TF; e += NT) {
        int ff = e & (TF - 1);
        int i  = e >> 4;                   // 0..63
        tab[ff * TSTRIDE + i * 8 + 5] = weights[(f0 + ff) * N_BSPLINES + i];
        tab[ff * TSTRIDE + i * 8 + 6] =
            (i < N_BSPLINES - 1) ? kL[(i + 5) * TF + ff] : 0.0f;
    }
    __syncthreads();

    const float* __restrict__ row = &tab[ft * TSTRIDE];

    float acc[QPT], r0[QPT], r1[QPT], r2[QPT], r3[QPT], r4[QPT];
    #pragma unroll
    for (int q = 0; q < QPT; ++q) {
        acc[q] = 0.0f;
        r0[q] = cube_f32(fmaxf(xq[q] - kL[0 * TF + ft], 0.0f));
        r1[q] = cube_f32(fmaxf(xq[q] - kL[1 * TF + ft], 0.0f));
        r2[q] = cube_f32(fmaxf(xq[q] - kL[2 * TF + ft], 0.0f));
        r3[q] = cube_f32(fmaxf(xq[q] - kL[3 * TF + ft], 0.0f));
        r4[q] = cube_f32(fmaxf(xq[q] - kL[4 * TF + ft], 0.0f));
    }

    #pragma unroll 8
    for (int i = 0; i < N_BSPLINES; ++i) {
        // 2x ds_read_b128, 16B-aligned, 2-way bank aliasing (free), shared by q.
        const float4 cv = *(const float4*)&row[i * 8];       // c0..c3
        const float4 cw = *(const float4*)&row[i * 8 + 4];   // c4, w, kn, pad
        #pragma unroll
        for (int q = 0; q < QPT; ++q) {
            float m0 = r0[q] * cv.x;
            float m1 = r1[q] * cv.y;
            float m2 = r2[q] * cv.z;
            float m3 = r3[q] * cv.w;
            float m4 = r4[q] * cw.x;
            // T3: masked-tail fold of m4 into lane 0, then shuffle-halves
            float t04  = m0 + m4;
            float t042 = t04 + m2;
            float t13  = m1 + m3;
            float sp   = t042 + t13;
            acc[q] = acc[q] + sp * cw.y;   // unfused, sequential i-sum
            r0[q] = r1[q]; r1[q] = r2[q]; r2[q] = r3[q]; r3[q] = r4[q];
            r4[q] = cube_f32(fmaxf(xq[q] - cw.z, 0.0f));   // dead at i=63
        }
    }

    #pragma unroll
    for (int q = 0; q < QPT; ++q)
        out[(b0 + bt + q * 16) * FEATURES + f0 + ft] = acc[q];
}

extern "C" void kernel_launch(void* const* d_in, const int* in_sizes, int n_in,
                              void* d_out, int out_size, void* d_ws, size_t ws_size,
                              hipStream_t stream) {
    const float* x       = (const float*)d_in[0];   // (2048, 512)
    const float* knots   = (const float*)d_in[1];   // (512, 68)
    const float* weights = (const float*)d_in[2];   // (512, 64)
    float*       out     = (float*)d_out;           // (2048, 512)

    const int blocks = (FEATURES / TF) * (BATCH / TB);   // 32 * 64 = 2048
    bspline_fused<<<blocks, NT, 0, stream>>>(x, knots, weights, out);
}

// Round 11
// 89.914 us; speedup vs baseline: 5.5891x; 1.2270x over previous
//
#include <hip/hip_runtime.h>

// Bit-exact recipe (locked R1-R7, absmax 0.0078 vs 0.106 thr):
//   cube  = (x*x)*x ;  j-sum = T3  ((m0+m4)+m2)+(m1+m3) ;  no fma anywhere
//   coef  = sequential ascending fp32 prod (b==j -> 1.0), IEEE divide
//   i-sum = sequential ascending, unfused mul/add
// R10 post-mortem: LDS-port bound. Per wave-iter: VALU 15 CU-cyc (QPT=2)
//   vs LDS ~29 CU-cyc (2x ds_read_b128 @12cyc + 2-way-b128 residual)
//   -> VALUBusy 61% measured == 15/29 predicted.
// R11: QPT=4 (TB=64) amortizes the same 2 b128/iter over 4 elements:
//   VALU 30 CU-cyc vs LDS 29 -> VALU-bound. Grid 1024 = exactly 4 blocks/CU
//   resident (37KB LDS), no tail. VALU floor 12.8us.
#pragma clang fp contract(off)

#define FEATURES   512
#define N_BSPLINES 64
#define N_KNOTS    68   // N_BSPLINES + DEGREE + 1
#define WINDOW     5    // DEGREE + 2
#define BATCH      2048

#define TF 16          // features per block (lane low bits -> coalesced 64B/16 lanes)
#define TB 64          // batch rows per block
#define QPT 4          // rows per thread
#define NT 256
#define TSTRIDE 516    // floats per ft row: 64*8 + 4 pad; 516%32=4 -> ft-quad rotation

__device__ __forceinline__ float cube_f32(float r) {
    float s = r * r;
    return s * r;
}

__global__ __launch_bounds__(NT) void bspline_fused(
    const float* __restrict__ x, const float* __restrict__ knots,
    const float* __restrict__ weights, float* __restrict__ out)
{
    __shared__ float kL[N_KNOTS * TF];     // [t][ft]
    __shared__ float tab[TF * TSTRIDE];    // [ft][i*8 + c]  c: 0-4 coef, 5 w, 6 kn

    const int tid  = threadIdx.x;
    const int fblk = blockIdx.x & (FEATURES / TF - 1);   // 0..31
    const int bblk = blockIdx.x >> 5;                    // 0..31
    const int f0   = fblk * TF;
    const int b0   = bblk * TB;

    const int ft = tid & (TF - 1);
    const int bt = tid >> 4;               // 0..15

    // x loads issued early; latency overlaps staging + coef build.
    float xq[QPT];
    #pragma unroll
    for (int q = 0; q < QPT; ++q)
        xq[q] = x[(b0 + bt + q * 16) * FEATURES + f0 + ft];

    // Stage knots [t][ft]; address == e -> consecutive lanes, conflict-free.
    for (int e = tid; e < N_KNOTS * TF; e += NT) {
        int ff = e & (TF - 1), t = e >> 4;
        kL[t * TF + ff] = knots[(f0 + ff) * N_KNOTS + t];
    }
    __syncthreads();

    // Coef build (bit-exact: sequential ascending fp32 product, b==j -> exact
    // 1.0, IEEE fp32 divide). Lane-adjacent e -> same (i,j), ff+1.
    for (int e = tid; e < N_BSPLINES * WINDOW * TF; e += NT) {
        int ff = e & (TF - 1);
        int m  = e >> 4;                   // 0..319
        int i = m / WINDOW, j = m % WINDOW;
        float kj = kL[(i + j) * TF + ff];
        float prod = 1.0f;
        #pragma unroll
        for (int b = 0; b < WINDOW; ++b) {
            float df = (b == j) ? 1.0f : (kL[(i + b) * TF + ff] - kj);
            prod = prod * df;
        }
        tab[ff * TSTRIDE + i * 8 + j] = 1.0f / prod;
    }
    // w and next-knot slots.
    for (int e = tid; e < N_BSPLINES * TF; e += NT) {
        int ff = e & (TF - 1);
        int i  = e >> 4;                   // 0..63
        tab[ff * TSTRIDE + i * 8 + 5] = weights[(f0 + ff) * N_BSPLINES + i];
        tab[ff * TSTRIDE + i * 8 + 6] =
            (i < N_BSPLINES - 1) ? kL[(i + 5) * TF + ff] : 0.0f;
    }
    __syncthreads();

    const float* __restrict__ row = &tab[ft * TSTRIDE];

    float acc[QPT], r0[QPT], r1[QPT], r2[QPT], r3[QPT], r4[QPT];
    #pragma unroll
    for (int q = 0; q < QPT; ++q) {
        acc[q] = 0.0f;
        r0[q] = cube_f32(fmaxf(xq[q] - kL[0 * TF + ft], 0.0f));
        r1[q] = cube_f32(fmaxf(xq[q] - kL[1 * TF + ft], 0.0f));
        r2[q] = cube_f32(fmaxf(xq[q] - kL[2 * TF + ft], 0.0f));
        r3[q] = cube_f32(fmaxf(xq[q] - kL[3 * TF + ft], 0.0f));
        r4[q] = cube_f32(fmaxf(xq[q] - kL[4 * TF + ft], 0.0f));
    }

    #pragma unroll 8
    for (int i = 0; i < N_BSPLINES; ++i) {
        // 2x ds_read_b128 (16B-aligned), shared across QPT=4 elements.
        const float4 cv = *(const float4*)&row[i * 8];       // c0..c3
        const float4 cw = *(const float4*)&row[i * 8 + 4];   // c4, w, kn, pad
        #pragma unroll
        for (int q = 0; q < QPT; ++q) {
            float m0 = r0[q] * cv.x;
            float m1 = r1[q] * cv.y;
            float m2 = r2[q] * cv.z;
            float m3 = r3[q] * cv.w;
            float m4 = r4[q] * cw.x;
            // T3: masked-tail fold of m4 into lane 0, then shuffle-halves
            float t04  = m0 + m4;
            float t042 = t04 + m2;
            float t13  = m1 + m3;
            float sp   = t042 + t13;
            acc[q] = acc[q] + sp * cw.y;   // unfused, sequential i-sum
            r0[q] = r1[q]; r1[q] = r2[q]; r2[q] = r3[q]; r3[q] = r4[q];
            r4[q] = cube_f32(fmaxf(xq[q] - cw.z, 0.0f));   // dead at i=63
        }
    }

    #pragma unroll
    for (int q = 0; q < QPT; ++q)
        out[(b0 + bt + q * 16) * FEATURES + f0 + ft] = acc[q];
}

extern "C" void kernel_launch(void* const* d_in, const int* in_sizes, int n_in,
                              void* d_out, int out_size, void* d_ws, size_t ws_size,
                              hipStream_t stream) {
    const float* x       = (const float*)d_in[0];   // (2048, 512)
    const float* knots   = (const float*)d_in[1];   // (512, 68)
    const float* weights = (const float*)d_in[2];   // (512, 64)
    float*       out     = (float*)d_out;           // (2048, 512)

    const int blocks = (FEATURES / TF) * (BATCH / TB);   // 32 * 32 = 1024
    bspline_fused<<<blocks, NT, 0, stream>>>(x, knots, weights, out);
}

// Round 12
// 86.428 us; speedup vs baseline: 5.8146x; 1.0403x over previous
//
#include <hip/hip_runtime.h>

// Bit-exact recipe (locked R1-R7, absmax 0.0078 vs 0.106 thr):
//   cube  = (x*x)*x ;  j-sum = T3  ((m0+m4)+m2)+(m1+m3) ;  no fma anywhere
//   coef  = sequential ascending fp32 prod (b==j -> 1.0), IEEE divide
//   i-sum = sequential ascending, unfused mul/add
// R11 post-mortem: eval ~41us, still LDS-port bound: main loop 20.5us/CU of
//   ds_read_b128 + ~10-16us/CU redundant in-block coef build (8-way-conflict
//   writes + div), rebuilt 32x per feature.
// R12: (1) coef build hoisted to prep kernel -> global padded table, eval
//   stages it with one flat coalesced float4 copy (layout-identical);
//   (2) QPT=8 -> main LDS 5.1us/CU < VALU floor 12.8us -> VALU-bound;
//   (3) period-5 manual unroll -> zero window-rotation v_movs.
#pragma clang fp contract(off)

#define FEATURES   512
#define N_BSPLINES 64
#define N_KNOTS    68   // N_BSPLINES + DEGREE + 1
#define WINDOW     5    // DEGREE + 2
#define BATCH      2048

#define TF 16          // features per block (lane low bits -> coalesced)
#define TB 128         // batch rows per block
#define QPT 8          // rows per thread
#define NT 256
#define TSTRIDE 516    // floats per feature row: 64*8 + 4 pad (516%32=4 -> 2-way banks, free)

__device__ __forceinline__ float cube_f32(float r) {
    float s = r * r;
    return s * r;
}

// One block per feature; thread t = i*5+j computes coef[i][j]; t<64 also
// writes w and next-knot slots. Bit-exact: sequential ascending fp32
// product (b==j -> exact 1.0), IEEE fp32 divide.
__global__ __launch_bounds__(320) void bspline_prep(
    const float* __restrict__ knots, const float* __restrict__ weights,
    float* __restrict__ g)
{
    const int f = blockIdx.x;
    const int t = threadIdx.x;             // 0..319
    const float* kf = knots + f * N_KNOTS;
    const int i = t / WINDOW, j = t % WINDOW;
    float kj = kf[i + j];
    float prod = 1.0f;
    #pragma unroll
    for (int b = 0; b < WINDOW; ++b) {
        float df = (b == j) ? 1.0f : (kf[i + b] - kj);
        prod = prod * df;
    }
    g[f * TSTRIDE + i * 8 + j] = 1.0f / prod;
    if (t < N_BSPLINES) {
        g[f * TSTRIDE + t * 8 + 5] = weights[f * N_BSPLINES + t];
        g[f * TSTRIDE + t * 8 + 6] = (t < N_BSPLINES - 1) ? kf[t + 5] : 0.0f;
        g[f * TSTRIDE + t * 8 + 7] = 0.0f;
    }
}

// One step of the i-loop; window registers passed in rotated order so the
// retire-and-refill needs no v_movs (period-5 unroll). RA retires.
#define STEP(I, RA, RB, RC, RD, RE)                                         \
    do {                                                                    \
        const float4 cv = *(const float4*)&row[(I) * 8];     /* c0..c3 */   \
        const float4 cw = *(const float4*)&row[(I) * 8 + 4]; /* c4,w,kn */  \
        _Pragma("unroll")                                                   \
        for (int q = 0; q < QPT; ++q) {                                     \
            float m0 = RA[q] * cv.x;                                        \
            float m1 = RB[q] * cv.y;                                        \
            float m2 = RC[q] * cv.z;                                        \
            float m3 = RD[q] * cv.w;                                        \
            float m4 = RE[q] * cw.x;                                        \
            float t04  = m0 + m4;   /* T3: masked-tail fold */              \
            float t042 = t04 + m2;                                          \
            float t13  = m1 + m3;                                           \
            float sp   = t042 + t13;                                        \
            acc[q] = acc[q] + sp * cw.y;  /* unfused sequential i-sum */    \
            RA[q] = cube_f32(fmaxf(xq[q] - cw.z, 0.0f));                    \
        }                                                                   \
    } while (0)

__global__ __launch_bounds__(NT) void bspline_eval(
    const float* __restrict__ x, const float* __restrict__ knots,
    const float* __restrict__ coefg, float* __restrict__ out)
{
    __shared__ float tab[TF * TSTRIDE];

    const int tid  = threadIdx.x;
    const int fblk = blockIdx.x & (FEATURES / TF - 1);   // 0..31
    const int bblk = blockIdx.x >> 5;                    // 0..15
    const int f0   = fblk * TF;
    const int b0   = bblk * TB;
    const int ft   = tid & (TF - 1);
    const int bt   = tid >> 4;             // 0..15

    // Early global loads: x rows and the first 5 knots (overlap staging).
    float xq[QPT];
    #pragma unroll
    for (int q = 0; q < QPT; ++q)
        xq[q] = x[(b0 + bt + q * 16) * FEATURES + f0 + ft];
    const float* kf = knots + (f0 + ft) * N_KNOTS;
    float k0 = kf[0], k1 = kf[1], k2 = kf[2], k3 = kf[3], k4 = kf[4];

    // Stage coef table: global layout for f0..f0+15 == LDS layout -> flat
    // coalesced float4 copy, conflict-free.
    const float4* __restrict__ gsrc = (const float4*)(coefg + (size_t)f0 * TSTRIDE);
    float4* __restrict__ tabv = (float4*)tab;
    for (int e = tid; e < TF * TSTRIDE / 4; e += NT)     // 2064 float4
        tabv[e] = gsrc[e];
    __syncthreads();

    const float* __restrict__ row = &tab[ft * TSTRIDE];

    float acc[QPT], r0[QPT], r1[QPT], r2[QPT], r3[QPT], r4[QPT];
    #pragma unroll
    for (int q = 0; q < QPT; ++q) {
        acc[q] = 0.0f;
        r0[q] = cube_f32(fmaxf(xq[q] - k0, 0.0f));
        r1[q] = cube_f32(fmaxf(xq[q] - k1, 0.0f));
        r2[q] = cube_f32(fmaxf(xq[q] - k2, 0.0f));
        r3[q] = cube_f32(fmaxf(xq[q] - k3, 0.0f));
        r4[q] = cube_f32(fmaxf(xq[q] - k4, 0.0f));
    }

    // 60 steps in groups of 5 (rotation period) + 4 tail steps: zero movs.
    for (int gi = 0; gi < 12; ++gi) {
        const int i = gi * 5;
        STEP(i + 0, r0, r1, r2, r3, r4);
        STEP(i + 1, r1, r2, r3, r4, r0);
        STEP(i + 2, r2, r3, r4, r0, r1);
        STEP(i + 3, r3, r4, r0, r1, r2);
        STEP(i + 4, r4, r0, r1, r2, r3);
    }
    STEP(60, r0, r1, r2, r3, r4);
    STEP(61, r1, r2, r3, r4, r0);
    STEP(62, r2, r3, r4, r0, r1);
    STEP(63, r3, r4, r0, r1, r2);          // kn slot = 0.0 -> dead cube

    #pragma unroll
    for (int q = 0; q < QPT; ++q)
        out[(b0 + bt + q * 16) * FEATURES + f0 + ft] = acc[q];
}

extern "C" void kernel_launch(void* const* d_in, const int* in_sizes, int n_in,
                              void* d_out, int out_size, void* d_ws, size_t ws_size,
                              hipStream_t stream) {
    const float* x       = (const float*)d_in[0];   // (2048, 512)
    const float* knots   = (const float*)d_in[1];   // (512, 68)
    const float* weights = (const float*)d_in[2];   // (512, 64)
    float*       out     = (float*)d_out;           // (2048, 512)
    float*       coefg   = (float*)d_ws;            // 512*516 floats ~ 1.01 MB

    bspline_prep<<<FEATURES, 320, 0, stream>>>(knots, weights, coefg);

    const int blocks = (FEATURES / TF) * (BATCH / TB);   // 32 * 16 = 512
    bspline_eval<<<blocks, NT, 0, stream>>>(x, knots, coefg, out);
}